// Round 16
// baseline (648.412 us; speedup 1.0000x reference)
//
#include <hip/hip_runtime.h>
#include <hip/hip_bf16.h>

#define NN 50000
#define EE 800000
#define NE 850000       // edges + self-loops
#define HID 128
#define NEG_SLOPE 0.2f
#define EPSN 1e-5f
#define NB 196          // buckets of 256 nodes
#define BCAP 6144       // bucket capacity (expected 4352 +- 64)
#define TB 4096         // edges per k_bin block
#define REP 128         // GraphNorm stats replicas
#define NPB 8           // nodes per k_gat_node block
#define LOG2E 1.4426950408889634f

typedef __attribute__((ext_vector_type(8))) short bf16x8;
typedef __attribute__((ext_vector_type(4))) float f32x4;

__device__ __forceinline__ unsigned short f2b(float f) {
    unsigned u = __float_as_uint(f);
    unsigned r = (u + 0x7FFFu + ((u >> 16) & 1u)) >> 16;
    return (unsigned short)r;
}
__device__ __forceinline__ float b2f(unsigned short u) {
    return __uint_as_float(((unsigned)u) << 16);
}
__device__ __forceinline__ float2 up2(unsigned u) {
    return make_float2(__uint_as_float(u << 16),
                       __uint_as_float(u & 0xFFFF0000u));
}
__device__ __forceinline__ float2 pk_fma(float2 a, float2 b, float2 c) {
    return make_float2(fmaf(a.x, b.x, c.x), fmaf(a.y, b.y, c.y));
}
__device__ __forceinline__ float2 pk_add(float2 a, float2 b) {
    return make_float2(a.x + b.x, a.y + b.y);
}
__device__ __forceinline__ float2 pk_leaky(float2 v) {
    return make_float2(fmaxf(v.x, NEG_SLOPE * v.x), fmaxf(v.y, NEG_SLOPE * v.y));
}

// ---------------- prep: W->bf16^T, x->bf16, zero bcnt + stats ----------------
__global__ void k_prep(const float* __restrict__ x, const float* __restrict__ Wl,
                       const float* __restrict__ Wr, const float* __restrict__ skip_W,
                       unsigned short* __restrict__ xb, unsigned short* __restrict__ wt,
                       unsigned short* __restrict__ st, int* __restrict__ bcnt,
                       float* __restrict__ stats) {
    int i = blockIdx.x * blockDim.x + threadIdx.x;
    if (i < NN * HID / 4) {
        float4 v = *(const float4*)&x[i * 4];
        ushort4 o = {f2b(v.x), f2b(v.y), f2b(v.z), f2b(v.w)};
        *(ushort4*)&xb[i * 4] = o;
    }
    if (i < NB) bcnt[i] = 0;
    if (i < REP * 256) stats[i] = 0.f;
    if (i < 4 * 256 * 128) {
        int l = i >> 15, rem = i & 32767;
        int c = rem >> 7, k = rem & 127;
        float v = (c < 128) ? Wl[l * 16384 + k * 128 + c]
                            : Wr[l * 16384 + k * 128 + (c - 128)];
        wt[i] = f2b(v);
    } else if (i < 4 * 256 * 128 + 128 * 128) {
        int j = i - 4 * 256 * 128;
        int c = j >> 7, k = j & 127;
        st[j] = f2b(skip_W[k * 128 + c]);
    }
}

// ---------------- CSR build: bucket sort ----------------
__global__ void __launch_bounds__(256) k_bin(const int* __restrict__ ei,
                                             int* __restrict__ bcnt,
                                             unsigned* __restrict__ bbuf) {
    __shared__ int hist[NB];
    __shared__ int gbase[NB];
    int t = threadIdx.x;
    for (int b = t; b < NB; b += 256) hist[b] = 0;
    __syncthreads();
    int e0 = blockIdx.x * TB;
    unsigned ent[16];
    int bkt[16];
#pragma unroll
    for (int k = 0; k < 16; k++) {
        int e = e0 + k * 256 + t;
        if (e < NE) {
            int src, dst;
            if (e < EE) { src = ei[e]; dst = ei[EE + e]; }
            else        { src = e - EE; dst = src; }
            int b = dst >> 8;
            ent[k] = ((unsigned)(dst & 255) << 17) | (unsigned)src;
            bkt[k] = b;
            atomicAdd(&hist[b], 1);
        } else bkt[k] = -1;
    }
    __syncthreads();
    for (int b = t; b < NB; b += 256) {
        int c = hist[b];
        gbase[b] = (c > 0) ? atomicAdd(&bcnt[b], c) : 0;
        hist[b] = 0;
    }
    __syncthreads();
#pragma unroll
    for (int k = 0; k < 16; k++) {
        int b = bkt[k];
        if (b >= 0) {
            int pos = gbase[b] + atomicAdd(&hist[b], 1);
            if (pos < BCAP) bbuf[(size_t)b * BCAP + pos] = ent[k];
        }
    }
}

// Per-bucket CSR with inline prefix scan; csr stores BYTE offsets (src*512).
__global__ void __launch_bounds__(256) k_bucket_csr(
    const unsigned* __restrict__ bbuf, const int* __restrict__ bcnt,
    int* __restrict__ row_ptr, int* __restrict__ csr_off) {
    __shared__ unsigned se[BCAP];
    __shared__ int pre[256];
    __shared__ int hist[256], scn[256], exs[256], cur[256];
    int b = blockIdx.x, t = threadIdx.x;
    int bv = (t < NB) ? bcnt[t] : 0;
    pre[t] = bv;
    __syncthreads();
    for (int o = 1; o < 256; o <<= 1) {
        int u = (t >= o) ? pre[t - o] : 0;
        __syncthreads();
        pre[t] += u;
        __syncthreads();
    }
    int cntb = bcnt[b];
    int base = pre[b] - cntb;          // exclusive prefix
    int cnt = min(cntb, BCAP);
    hist[t] = 0;
    cur[t] = 0;
    __syncthreads();
    for (int j = t; j < cnt; j += 256) {
        unsigned e = bbuf[(size_t)b * BCAP + j];
        se[j] = e;
        atomicAdd(&hist[e >> 17], 1);
    }
    __syncthreads();
    int v = hist[t];
    scn[t] = v;
    __syncthreads();
    for (int o = 1; o < 256; o <<= 1) {
        int u = (t >= o) ? scn[t - o] : 0;
        __syncthreads();
        scn[t] += u;
        __syncthreads();
    }
    int ex = scn[t] - v;
    exs[t] = ex;
    int node = b * 256 + t;
    if (node < NN) row_ptr[node] = base + ex;
    if (b == NB - 1 && t == 0) row_ptr[NN] = NE;
    __syncthreads();
    for (int j = t; j < cnt; j += 256) {
        unsigned e = se[j];
        int dl = e >> 17;
        int p = exs[dl] + atomicAdd(&cur[dl], 1);
        csr_off[base + p] = (int)((e & 0x1FFFFu) << 9);   // src * 512 bytes
    }
}

// ---------------- MFMA GEMM (layer 0 only): xlr = Xb @ Wcat ----------------
__global__ void __launch_bounds__(256) k_gemm_dual_mfma(
    const unsigned short* __restrict__ Xb, const unsigned short* __restrict__ WT,
    unsigned short* __restrict__ C) {
    int w = threadIdx.x >> 6, lane = threadIdx.x & 63;
    int quad = lane >> 4, l16 = lane & 15;
    int r0 = blockIdx.x * 64 + w * 16;
    int lrow = r0 + l16; if (lrow >= NN) lrow = NN - 1;
    const unsigned short* arow = Xb + (size_t)lrow * 128 + quad * 8;
    bf16x8 a[4];
#pragma unroll
    for (int ks = 0; ks < 4; ks++) a[ks] = *(const bf16x8*)(arow + ks * 32);
    f32x4 acc[16];
#pragma unroll
    for (int ct = 0; ct < 16; ct++) acc[ct] = (f32x4){0, 0, 0, 0};
#pragma unroll
    for (int ct = 0; ct < 16; ct++) {
        const unsigned short* bbase = WT + (size_t)(ct * 16 + l16) * 128 + quad * 8;
#pragma unroll
        for (int ks = 0; ks < 4; ks++) {
            bf16x8 b = *(const bf16x8*)(bbase + ks * 32);
            acc[ct] = __builtin_amdgcn_mfma_f32_16x16x32_bf16(a[ks], b, acc[ct], 0, 0, 0);
        }
    }
    int sr = r0 + quad * 4;
#pragma unroll
    for (int ct = 0; ct < 16; ct++) {
#pragma unroll
        for (int r = 0; r < 4; r++) {
            int rr = sr + r;
            if (rr < NN) C[(size_t)rr * 256 + ct * 16 + l16] = f2b(acc[ct][r]);
        }
    }
}

// ---------------- reduce stats replicas -> scale/offset; re-zero ----------------
__global__ void __launch_bounds__(1024) k_finalize(
    float* __restrict__ stats, const float* __restrict__ gn_w,
    const float* __restrict__ gn_b, const float* __restrict__ gn_ms,
    float* __restrict__ scoff) {
    __shared__ float red[1024];
    __shared__ float tot[256];
    int t = threadIdx.x;
    int col = t & 255, part = t >> 8;
    float s = 0.f;
    for (int r = part * (REP / 4); r < (part + 1) * (REP / 4); r++)
        s += stats[(size_t)r * 256 + col];
    red[t] = s;
    __syncthreads();
    if (part == 0) tot[col] = red[col] + red[col + 256] + red[col + 512] + red[col + 768];
    __syncthreads();
    for (int j = t; j < REP * 256; j += 1024) stats[j] = 0.f;
    if (t < 128) {
        const float invN = 1.0f / (float)NN;
        float mean = tot[t] * invN;
        float ex2 = tot[128 + t] * invN;
        float ms = gn_ms[t];
        float var = ex2 - (2.f * ms - ms * ms) * mean * mean;
        float wsc = gn_w[t] * rsqrtf(var + EPSN);
        scoff[t] = wsc;
        scoff[128 + t] = gn_b[t] - wsc * ms * mean;
    }
}

// ---------------- skip-GEMM core: acc[8] = ELU(scale*h+off) @ skipW ----------------
__device__ __forceinline__ void skip_core(
    const unsigned short* __restrict__ hbufb, const float* __restrict__ scoff,
    const unsigned short* __restrict__ ST, int lrow, int quad, int l16,
    f32x4 (&acc)[8]) {
    const unsigned short* hrow = hbufb + (size_t)lrow * 128 + quad * 8;
#pragma unroll
    for (int ct = 0; ct < 8; ct++) acc[ct] = (f32x4){0, 0, 0, 0};
#pragma unroll
    for (int ks = 0; ks < 4; ks++) {
        int k0 = ks * 32;
        int kc = quad * 8 + k0;
        uint4 hw = *(const uint4*)(hrow + k0);
        float2 h01 = up2(hw.x), h23 = up2(hw.y), h45 = up2(hw.z), h67 = up2(hw.w);
        float4 sc0 = *(const float4*)(scoff + kc);
        float4 sc1 = *(const float4*)(scoff + kc + 4);
        float4 of0 = *(const float4*)(scoff + 128 + kc);
        float4 of1 = *(const float4*)(scoff + 128 + kc + 4);
        float e[8];
        e[0] = fmaf(sc0.x, h01.x, of0.x); e[1] = fmaf(sc0.y, h01.y, of0.y);
        e[2] = fmaf(sc0.z, h23.x, of0.z); e[3] = fmaf(sc0.w, h23.y, of0.w);
        e[4] = fmaf(sc1.x, h45.x, of1.x); e[5] = fmaf(sc1.y, h45.y, of1.y);
        e[6] = fmaf(sc1.z, h67.x, of1.z); e[7] = fmaf(sc1.w, h67.y, of1.w);
        bf16x8 af;
#pragma unroll
        for (int j = 0; j < 8; j++) {
            float v = e[j];
            v = (v > 0.f) ? v : (__expf(v) - 1.f);
            af[j] = (short)f2b(v);
        }
#pragma unroll
        for (int ct = 0; ct < 8; ct++) {
            bf16x8 b = *(const bf16x8*)(ST + (size_t)(ct * 16 + l16) * 128 + quad * 8 + k0);
            acc[ct] = __builtin_amdgcn_mfma_f32_16x16x32_bf16(af, b, acc[ct], 0, 0, 0);
        }
    }
}

// ---------------- fused skip + next-layer dual GEMM ----------------
__global__ void __launch_bounds__(256) k_skip_dual(
    const unsigned short* __restrict__ hbufb, const float* __restrict__ scoff,
    const unsigned short* __restrict__ ST, const float* __restrict__ skip_b,
    unsigned short* __restrict__ Xb16,
    const unsigned short* __restrict__ WTnext, unsigned short* __restrict__ xlr) {
    __shared__ unsigned short tileX[64][136];      // block-wide new X (bf16)
    __shared__ unsigned short tileC[4][16][264];   // per-wave xlr staging
    int t = threadIdx.x;
    int w = t >> 6, lane = t & 63;
    int quad = lane >> 4, l16 = lane & 15;
    int r0b = blockIdx.x * 64;
    int r0 = r0b + w * 16;
    int lrow = r0 + l16; if (lrow >= NN) lrow = NN - 1;
#pragma unroll
    for (int it = 0; it < 4; it++) {
        int idx = it * 256 + t;
        int row = idx >> 4;
        int c8 = (idx & 15) * 8;
        int rr = r0b + row;
        uint4 v = (rr < NN) ? *(const uint4*)&Xb16[(size_t)rr * 128 + c8]
                            : (uint4){0, 0, 0, 0};
        *(uint4*)&tileX[row][c8] = v;
    }
    f32x4 acc[8];
    skip_core(hbufb, scoff, ST, lrow, quad, l16, acc);
    __syncthreads();
#pragma unroll
    for (int ct = 0; ct < 8; ct++) {
        int c = ct * 16 + l16;
        float sb = skip_b[c];
#pragma unroll
        for (int r = 0; r < 4; r++) {
            int wrow = w * 16 + quad * 4 + r;
            float v = b2f(tileX[wrow][c]) + acc[ct][r] + sb;
            tileX[wrow][c] = f2b(v);
        }
    }
    __syncthreads();
#pragma unroll
    for (int it = 0; it < 4; it++) {
        int idx = it * 256 + t;
        int row = idx >> 4;
        int c8 = (idx & 15) * 8;
        int rr = r0b + row;
        if (rr < NN) *(uint4*)&Xb16[(size_t)rr * 128 + c8] = *(const uint4*)&tileX[row][c8];
    }
    int wrowA = w * 16 + l16;
    bf16x8 a[4];
#pragma unroll
    for (int ks = 0; ks < 4; ks++)
        a[ks] = *(const bf16x8*)&tileX[wrowA][quad * 8 + ks * 32];
    f32x4 dacc[16];
#pragma unroll
    for (int ct = 0; ct < 16; ct++) dacc[ct] = (f32x4){0, 0, 0, 0};
#pragma unroll
    for (int ct = 0; ct < 16; ct++) {
        const unsigned short* bbase = WTnext + (size_t)(ct * 16 + l16) * 128 + quad * 8;
#pragma unroll
        for (int ks = 0; ks < 4; ks++) {
            bf16x8 b = *(const bf16x8*)(bbase + ks * 32);
            dacc[ct] = __builtin_amdgcn_mfma_f32_16x16x32_bf16(a[ks], b, dacc[ct], 0, 0, 0);
        }
    }
#pragma unroll
    for (int ct = 0; ct < 16; ct++) {
#pragma unroll
        for (int r = 0; r < 4; r++)
            tileC[w][quad * 4 + r][ct * 16 + l16] = f2b(dacc[ct][r]);
    }
    __syncthreads();
#pragma unroll
    for (int it = 0; it < 8; it++) {
        int idx = it * 64 + lane;
        int row = idx >> 5;
        int c8 = (idx & 31) * 8;
        int rr = r0 + row;
        if (rr < NN) *(uint4*)&xlr[(size_t)rr * 256 + c8] = *(const uint4*)&tileC[w][row][c8];
    }
}

// ---------------- fused skip + final fc (last layer) ----------------
__global__ void __launch_bounds__(256) k_skip_fc(
    const unsigned short* __restrict__ hbufb, const float* __restrict__ scoff,
    const unsigned short* __restrict__ ST, const float* __restrict__ skip_b,
    const unsigned short* __restrict__ Xb16,
    const float* __restrict__ fc_W, const float* __restrict__ fc_b,
    float* __restrict__ out) {
    __shared__ unsigned short tileX[64][136];
    int t = threadIdx.x;
    int w = t >> 6, lane = t & 63;
    int quad = lane >> 4, l16 = lane & 15;
    int r0b = blockIdx.x * 64;
    int r0 = r0b + w * 16;
    int lrow = r0 + l16; if (lrow >= NN) lrow = NN - 1;
#pragma unroll
    for (int it = 0; it < 4; it++) {
        int idx = it * 256 + t;
        int row = idx >> 4;
        int c8 = (idx & 15) * 8;
        int rr = r0b + row;
        uint4 v = (rr < NN) ? *(const uint4*)&Xb16[(size_t)rr * 128 + c8]
                            : (uint4){0, 0, 0, 0};
        *(uint4*)&tileX[row][c8] = v;
    }
    f32x4 acc[8];
    skip_core(hbufb, scoff, ST, lrow, quad, l16, acc);
    __syncthreads();
    float p[4] = {0.f, 0.f, 0.f, 0.f};
#pragma unroll
    for (int ct = 0; ct < 8; ct++) {
        int c = ct * 16 + l16;
        float sb = skip_b[c];
        float fw = fc_W[c];
#pragma unroll
        for (int r = 0; r < 4; r++) {
            int wrow = w * 16 + quad * 4 + r;
            float v = b2f(tileX[wrow][c]) + acc[ct][r] + sb;
            p[r] = fmaf(v, fw, p[r]);
        }
    }
#pragma unroll
    for (int r = 0; r < 4; r++) {
        p[r] += __shfl_xor(p[r], 1);
        p[r] += __shfl_xor(p[r], 2);
        p[r] += __shfl_xor(p[r], 4);
        p[r] += __shfl_xor(p[r], 8);
    }
    if (l16 == 0) {
        float fb = fc_b[0];
#pragma unroll
        for (int r = 0; r < 4; r++) {
            int rr = r0 + quad * 4 + r;
            if (rr < NN) out[rr] = p[r] + fb;
        }
    }
}

// ---------------- fused GATv2: 8 slots stride one node; 2x-unrolled ping-pong ----------------
// att pre-scaled by log2(e) so score exps become a single v_exp_f32 (exp2f).
__global__ void __launch_bounds__(128) k_gat_node(
    const unsigned short* __restrict__ xlr,
    const float* __restrict__ att, const float* __restrict__ conv_b,
    const int* __restrict__ row_ptr, const int* __restrict__ csr_off,
    unsigned short* __restrict__ houtb, float* __restrict__ stats) {
    int t = threadIdx.x;
    int g = t >> 4;          // slot 0..7
    int l = t & 15;          // lane in slot: owns channels 8l..8l+7
    const char* xbytes = (const char*)xlr;
    int lofs = 16 * l;
    float2 at2[4];
    {
        float4 a0 = *(const float4*)&att[8 * l];
        float4 a1 = *(const float4*)&att[8 * l + 4];
        at2[0] = make_float2(a0.x * LOG2E, a0.y * LOG2E);
        at2[1] = make_float2(a0.z * LOG2E, a0.w * LOG2E);
        at2[2] = make_float2(a1.x * LOG2E, a1.y * LOG2E);
        at2[3] = make_float2(a1.z * LOG2E, a1.w * LOG2E);
    }
    float cb = conv_b[t];
    int i0 = blockIdx.x * NPB;
    int rp[NPB + 1];
#pragma unroll
    for (int k = 0; k <= NPB; k++) rp[k] = row_ptr[i0 + k];   // wave-uniform -> scalar
    __shared__ float s_acc[2][8][16][12];
    __shared__ float s_den[2][8][16];
    float ssum = 0.f, ssum2 = 0.f;
    uint4 xr_next = *(const uint4*)(xbytes + (size_t)i0 * 512 + 256 + lofs);
    for (int nn = 0; nn < NPB; nn++) {
        int i = i0 + nn;
        uint4 xr_raw = xr_next;
        if (nn + 1 < NPB)
            xr_next = *(const uint4*)(xbytes + (size_t)(i + 1) * 512 + 256 + lofs);
        float2 xr2[4];
        xr2[0] = up2(xr_raw.x); xr2[1] = up2(xr_raw.y);
        xr2[2] = up2(xr_raw.z); xr2[3] = up2(xr_raw.w);
        int start = rp[nn], end = rp[nn + 1];
        float den = 0.f;
        float2 acc[4];
#pragma unroll
        for (int k = 0; k < 4; k++) acc[k] = make_float2(0.f, 0.f);
        int j = start + g;
        bool v0 = j < end;
        bool v1 = (j + 8) < end;
        int o0 = v0 ? csr_off[j] : 0;
        int o1 = v1 ? csr_off[j + 8] : 0;
        uint4 xw0 = {0,0,0,0}, xw1 = {0,0,0,0};
        if (v0) xw0 = *(const uint4*)(xbytes + (size_t)(unsigned)o0 + lofs);
        if (v1) xw1 = *(const uint4*)(xbytes + (size_t)(unsigned)o1 + lofs);
        while (v0) {
            // stage A: process edge j (always valid in-loop); prefetch j+16
            bool vA = (j + 16) < end;
            int oA = vA ? csr_off[j + 16] : 0;
            uint4 pfA = vA ? *(const uint4*)(xbytes + (size_t)(unsigned)oA + lofs)
                           : (uint4){0, 0, 0, 0};
            {
                float2 f0 = up2(xw0.x), f1 = up2(xw0.y), f2v = up2(xw0.z), f3 = up2(xw0.w);
                float2 ps = make_float2(0.f, 0.f);
                ps = pk_fma(at2[0], pk_leaky(pk_add(f0, xr2[0])), ps);
                ps = pk_fma(at2[1], pk_leaky(pk_add(f1, xr2[1])), ps);
                ps = pk_fma(at2[2], pk_leaky(pk_add(f2v, xr2[2])), ps);
                ps = pk_fma(at2[3], pk_leaky(pk_add(f3, xr2[3])), ps);
                float p = ps.x + ps.y;
                p += __shfl_xor(p, 1);
                p += __shfl_xor(p, 2);
                float w = exp2f(p);
                den += w;
                float2 w2 = make_float2(w, w);
                acc[0] = pk_fma(w2, f0, acc[0]);
                acc[1] = pk_fma(w2, f1, acc[1]);
                acc[2] = pk_fma(w2, f2v, acc[2]);
                acc[3] = pk_fma(w2, f3, acc[3]);
            }
            xw0 = pfA;
            // stage B: process edge j+8 (guarded); prefetch j+24
            bool vB = (j + 24) < end;
            int oB = vB ? csr_off[j + 24] : 0;
            uint4 pfB = vB ? *(const uint4*)(xbytes + (size_t)(unsigned)oB + lofs)
                           : (uint4){0, 0, 0, 0};
            {
                float2 f0 = up2(xw1.x), f1 = up2(xw1.y), f2v = up2(xw1.z), f3 = up2(xw1.w);
                float2 ps = make_float2(0.f, 0.f);
                ps = pk_fma(at2[0], pk_leaky(pk_add(f0, xr2[0])), ps);
                ps = pk_fma(at2[1], pk_leaky(pk_add(f1, xr2[1])), ps);
                ps = pk_fma(at2[2], pk_leaky(pk_add(f2v, xr2[2])), ps);
                ps = pk_fma(at2[3], pk_leaky(pk_add(f3, xr2[3])), ps);
                float p = ps.x + ps.y;
                p += __shfl_xor(p, 1);
                p += __shfl_xor(p, 2);
                float w = exp2f(p);
                w = v1 ? w : 0.f;          // tail guard
                den += w;
                float2 w2 = make_float2(w, w);
                acc[0] = pk_fma(w2, f0, acc[0]);
                acc[1] = pk_fma(w2, f1, acc[1]);
                acc[2] = pk_fma(w2, f2v, acc[2]);
                acc[3] = pk_fma(w2, f3, acc[3]);
            }
            xw1 = pfB;
            j += 16;
            v0 = vA;
            v1 = vB;
        }
        int par = nn & 1;
        *(float4*)&s_acc[par][g][l][0] = make_float4(acc[0].x, acc[0].y, acc[1].x, acc[1].y);
        *(float4*)&s_acc[par][g][l][4] = make_float4(acc[2].x, acc[2].y, acc[3].x, acc[3].y);
        s_den[par][g][l] = den;
        __syncthreads();
        int cl = t >> 3, cj = t & 7;
        float a = 0.f, d = 0.f;
#pragma unroll
        for (int gg = 0; gg < 8; gg++) {
            a += s_acc[par][gg][cl][cj];
            d += s_den[par][gg][cl];
        }
        float hv = a / d + cb;
        houtb[(size_t)i * HID + t] = f2b(hv);
        ssum += hv;
        ssum2 += hv * hv;
    }
    float* srep = stats + (size_t)(blockIdx.x & (REP - 1)) * 256;
    atomicAdd(&srep[t], ssum);
    atomicAdd(&srep[128 + t], ssum2);
}

extern "C" void kernel_launch(void* const* d_in, const int* in_sizes, int n_in,
                              void* d_out, int out_size, void* d_ws, size_t ws_size,
                              hipStream_t stream) {
    const float* x_in   = (const float*)d_in[0];
    const int*   ei     = (const int*)d_in[1];
    const float* Wl     = (const float*)d_in[2];
    const float* Wr     = (const float*)d_in[3];
    const float* att    = (const float*)d_in[4];
    const float* conv_b = (const float*)d_in[5];
    const float* gn_w   = (const float*)d_in[6];
    const float* gn_b   = (const float*)d_in[7];
    const float* gn_ms  = (const float*)d_in[8];
    const float* skip_W = (const float*)d_in[9];
    const float* skip_b = (const float*)d_in[10];
    const float* fc_W   = (const float*)d_in[11];
    const float* fc_b   = (const float*)d_in[12];
    float* out = (float*)d_out;

    // workspace carve
    float* ws = (float*)d_ws;
    float* stats = ws;                              // REP * 256
    float* scoff = stats + REP * 256;               // 256
    unsigned short* xlr   = (unsigned short*)(scoff + 256);  // N*256 bf16
    unsigned short* b16X  = xlr + (size_t)NN * 256; // N*HID bf16 (residual stream)
    unsigned short* hbufb = b16X + NN * HID;        // N*HID bf16
    unsigned short* wt    = hbufb + NN * HID;       // 4*256*128
    unsigned short* st    = wt + 4 * 256 * 128;     // 128*128
    int* row_ptr = (int*)(st + 128 * 128);          // N+1
    int* bcnt    = row_ptr + NN + 1;                // NB
    int* csr_off = bcnt + NB;                       // NE (byte offsets)
    unsigned* bbuf = (unsigned*)(csr_off + NE);     // NB*BCAP

    k_prep<<<(NN * HID / 4 + 255) / 256, 256, 0, stream>>>(
        x_in, Wl, Wr, skip_W, b16X, wt, st, bcnt, stats);

    // CSR build via bucket sort
    k_bin<<<(NE + TB - 1) / TB, 256, 0, stream>>>(ei, bcnt, bbuf);
    k_bucket_csr<<<NB, 256, 0, stream>>>(bbuf, bcnt, row_ptr, csr_off);

    const int rtiles = (NN + 63) / 64;              // 782
    const int gat_blocks = (NN + NPB - 1) / NPB;    // 6250
    k_gemm_dual_mfma<<<rtiles, 256, 0, stream>>>(b16X, wt, xlr);
    for (int l = 0; l < 4; l++) {
        k_gat_node<<<gat_blocks, 128, 0, stream>>>(
            xlr, att + l * HID, conv_b + l * HID, row_ptr, csr_off,
            hbufb, stats);
        k_finalize<<<1, 1024, 0, stream>>>(stats, gn_w + l * HID,
                                           gn_b + l * HID, gn_ms + l * HID, scoff);
        if (l < 3) {
            k_skip_dual<<<rtiles, 256, 0, stream>>>(
                hbufb, scoff, st, skip_b, b16X,
                wt + (size_t)(l + 1) * 256 * 128, xlr);
        } else {
            k_skip_fc<<<rtiles, 256, 0, stream>>>(
                hbufb, scoff, st, skip_b, b16X, fc_W, fc_b, out);
        }
    }
}

// Round 17
// 587.509 us; speedup vs baseline: 1.1037x; 1.1037x over previous
//
#include <hip/hip_runtime.h>
#include <hip/hip_bf16.h>

#define NN 50000
#define EE 800000
#define NE 850000       // edges + self-loops
#define HID 128
#define NEG_SLOPE 0.2f
#define EPSN 1e-5f
#define NB 196          // buckets of 256 nodes
#define BCAP 6144       // bucket capacity (expected 4352 +- 64)
#define TB 4096         // edges per k_bin block
#define REP 128         // GraphNorm stats replicas
#define NPB 8           // nodes per k_gat_node block
#define LOG2E 1.4426950408889634f

typedef __attribute__((ext_vector_type(8))) short bf16x8;
typedef __attribute__((ext_vector_type(4))) float f32x4;

__device__ __forceinline__ unsigned short f2b(float f) {
    unsigned u = __float_as_uint(f);
    unsigned r = (u + 0x7FFFu + ((u >> 16) & 1u)) >> 16;
    return (unsigned short)r;
}
__device__ __forceinline__ float b2f(unsigned short u) {
    return __uint_as_float(((unsigned)u) << 16);
}
__device__ __forceinline__ float2 up2(unsigned u) {
    return make_float2(__uint_as_float(u << 16),
                       __uint_as_float(u & 0xFFFF0000u));
}
__device__ __forceinline__ float2 pk_fma(float2 a, float2 b, float2 c) {
    return make_float2(fmaf(a.x, b.x, c.x), fmaf(a.y, b.y, c.y));
}
__device__ __forceinline__ float2 pk_add(float2 a, float2 b) {
    return make_float2(a.x + b.x, a.y + b.y);
}
__device__ __forceinline__ float2 pk_leaky(float2 v) {
    return make_float2(fmaxf(v.x, NEG_SLOPE * v.x), fmaxf(v.y, NEG_SLOPE * v.y));
}

// ---------------- prep: W->bf16^T, x->bf16, zero bcnt + stats ----------------
__global__ void k_prep(const float* __restrict__ x, const float* __restrict__ Wl,
                       const float* __restrict__ Wr, const float* __restrict__ skip_W,
                       unsigned short* __restrict__ xb, unsigned short* __restrict__ wt,
                       unsigned short* __restrict__ st, int* __restrict__ bcnt,
                       float* __restrict__ stats) {
    int i = blockIdx.x * blockDim.x + threadIdx.x;
    if (i < NN * HID / 4) {
        float4 v = *(const float4*)&x[i * 4];
        ushort4 o = {f2b(v.x), f2b(v.y), f2b(v.z), f2b(v.w)};
        *(ushort4*)&xb[i * 4] = o;
    }
    if (i < NB) bcnt[i] = 0;
    if (i < REP * 256) stats[i] = 0.f;
    if (i < 4 * 256 * 128) {
        int l = i >> 15, rem = i & 32767;
        int c = rem >> 7, k = rem & 127;
        float v = (c < 128) ? Wl[l * 16384 + k * 128 + c]
                            : Wr[l * 16384 + k * 128 + (c - 128)];
        wt[i] = f2b(v);
    } else if (i < 4 * 256 * 128 + 128 * 128) {
        int j = i - 4 * 256 * 128;
        int c = j >> 7, k = j & 127;
        st[j] = f2b(skip_W[k * 128 + c]);
    }
}

// ---------------- CSR build: bucket sort ----------------
__global__ void __launch_bounds__(256) k_bin(const int* __restrict__ ei,
                                             int* __restrict__ bcnt,
                                             unsigned* __restrict__ bbuf) {
    __shared__ int hist[NB];
    __shared__ int gbase[NB];
    int t = threadIdx.x;
    for (int b = t; b < NB; b += 256) hist[b] = 0;
    __syncthreads();
    int e0 = blockIdx.x * TB;
    unsigned ent[16];
    int bkt[16];
#pragma unroll
    for (int k = 0; k < 16; k++) {
        int e = e0 + k * 256 + t;
        if (e < NE) {
            int src, dst;
            if (e < EE) { src = ei[e]; dst = ei[EE + e]; }
            else        { src = e - EE; dst = src; }
            int b = dst >> 8;
            ent[k] = ((unsigned)(dst & 255) << 17) | (unsigned)src;
            bkt[k] = b;
            atomicAdd(&hist[b], 1);
        } else bkt[k] = -1;
    }
    __syncthreads();
    for (int b = t; b < NB; b += 256) {
        int c = hist[b];
        gbase[b] = (c > 0) ? atomicAdd(&bcnt[b], c) : 0;
        hist[b] = 0;
    }
    __syncthreads();
#pragma unroll
    for (int k = 0; k < 16; k++) {
        int b = bkt[k];
        if (b >= 0) {
            int pos = gbase[b] + atomicAdd(&hist[b], 1);
            if (pos < BCAP) bbuf[(size_t)b * BCAP + pos] = ent[k];
        }
    }
}

// Per-bucket CSR with inline prefix scan; csr stores BYTE offsets (src*512).
__global__ void __launch_bounds__(256) k_bucket_csr(
    const unsigned* __restrict__ bbuf, const int* __restrict__ bcnt,
    int* __restrict__ row_ptr, int* __restrict__ csr_off) {
    __shared__ unsigned se[BCAP];
    __shared__ int pre[256];
    __shared__ int hist[256], scn[256], exs[256], cur[256];
    int b = blockIdx.x, t = threadIdx.x;
    int bv = (t < NB) ? bcnt[t] : 0;
    pre[t] = bv;
    __syncthreads();
    for (int o = 1; o < 256; o <<= 1) {
        int u = (t >= o) ? pre[t - o] : 0;
        __syncthreads();
        pre[t] += u;
        __syncthreads();
    }
    int cntb = bcnt[b];
    int base = pre[b] - cntb;          // exclusive prefix
    int cnt = min(cntb, BCAP);
    hist[t] = 0;
    cur[t] = 0;
    __syncthreads();
    for (int j = t; j < cnt; j += 256) {
        unsigned e = bbuf[(size_t)b * BCAP + j];
        se[j] = e;
        atomicAdd(&hist[e >> 17], 1);
    }
    __syncthreads();
    int v = hist[t];
    scn[t] = v;
    __syncthreads();
    for (int o = 1; o < 256; o <<= 1) {
        int u = (t >= o) ? scn[t - o] : 0;
        __syncthreads();
        scn[t] += u;
        __syncthreads();
    }
    int ex = scn[t] - v;
    exs[t] = ex;
    int node = b * 256 + t;
    if (node < NN) row_ptr[node] = base + ex;
    if (b == NB - 1 && t == 0) row_ptr[NN] = NE;
    __syncthreads();
    for (int j = t; j < cnt; j += 256) {
        unsigned e = se[j];
        int dl = e >> 17;
        int p = exs[dl] + atomicAdd(&cur[dl], 1);
        csr_off[base + p] = (int)((e & 0x1FFFFu) << 9);   // src * 512 bytes
    }
}

// ---------------- MFMA GEMM (layer 0 only): xlr = Xb @ Wcat ----------------
__global__ void __launch_bounds__(256) k_gemm_dual_mfma(
    const unsigned short* __restrict__ Xb, const unsigned short* __restrict__ WT,
    unsigned short* __restrict__ C) {
    int w = threadIdx.x >> 6, lane = threadIdx.x & 63;
    int quad = lane >> 4, l16 = lane & 15;
    int r0 = blockIdx.x * 64 + w * 16;
    int lrow = r0 + l16; if (lrow >= NN) lrow = NN - 1;
    const unsigned short* arow = Xb + (size_t)lrow * 128 + quad * 8;
    bf16x8 a[4];
#pragma unroll
    for (int ks = 0; ks < 4; ks++) a[ks] = *(const bf16x8*)(arow + ks * 32);
    f32x4 acc[16];
#pragma unroll
    for (int ct = 0; ct < 16; ct++) acc[ct] = (f32x4){0, 0, 0, 0};
#pragma unroll
    for (int ct = 0; ct < 16; ct++) {
        const unsigned short* bbase = WT + (size_t)(ct * 16 + l16) * 128 + quad * 8;
#pragma unroll
        for (int ks = 0; ks < 4; ks++) {
            bf16x8 b = *(const bf16x8*)(bbase + ks * 32);
            acc[ct] = __builtin_amdgcn_mfma_f32_16x16x32_bf16(a[ks], b, acc[ct], 0, 0, 0);
        }
    }
    int sr = r0 + quad * 4;
#pragma unroll
    for (int ct = 0; ct < 16; ct++) {
#pragma unroll
        for (int r = 0; r < 4; r++) {
            int rr = sr + r;
            if (rr < NN) C[(size_t)rr * 256 + ct * 16 + l16] = f2b(acc[ct][r]);
        }
    }
}

// ---------------- reduce stats replicas -> scale/offset; re-zero ----------------
__global__ void __launch_bounds__(1024) k_finalize(
    float* __restrict__ stats, const float* __restrict__ gn_w,
    const float* __restrict__ gn_b, const float* __restrict__ gn_ms,
    float* __restrict__ scoff) {
    __shared__ float red[1024];
    __shared__ float tot[256];
    int t = threadIdx.x;
    int col = t & 255, part = t >> 8;
    float s = 0.f;
    for (int r = part * (REP / 4); r < (part + 1) * (REP / 4); r++)
        s += stats[(size_t)r * 256 + col];
    red[t] = s;
    __syncthreads();
    if (part == 0) tot[col] = red[col] + red[col + 256] + red[col + 512] + red[col + 768];
    __syncthreads();
    for (int j = t; j < REP * 256; j += 1024) stats[j] = 0.f;
    if (t < 128) {
        const float invN = 1.0f / (float)NN;
        float mean = tot[t] * invN;
        float ex2 = tot[128 + t] * invN;
        float ms = gn_ms[t];
        float var = ex2 - (2.f * ms - ms * ms) * mean * mean;
        float wsc = gn_w[t] * rsqrtf(var + EPSN);
        scoff[t] = wsc;
        scoff[128 + t] = gn_b[t] - wsc * ms * mean;
    }
}

// ---------------- skip-GEMM core: acc[8] = ELU(scale*h+off) @ skipW ----------------
__device__ __forceinline__ void skip_core(
    const unsigned short* __restrict__ hbufb, const float* __restrict__ scoff,
    const unsigned short* __restrict__ ST, int lrow, int quad, int l16,
    f32x4 (&acc)[8]) {
    const unsigned short* hrow = hbufb + (size_t)lrow * 128 + quad * 8;
#pragma unroll
    for (int ct = 0; ct < 8; ct++) acc[ct] = (f32x4){0, 0, 0, 0};
#pragma unroll
    for (int ks = 0; ks < 4; ks++) {
        int k0 = ks * 32;
        int kc = quad * 8 + k0;
        uint4 hw = *(const uint4*)(hrow + k0);
        float2 h01 = up2(hw.x), h23 = up2(hw.y), h45 = up2(hw.z), h67 = up2(hw.w);
        float4 sc0 = *(const float4*)(scoff + kc);
        float4 sc1 = *(const float4*)(scoff + kc + 4);
        float4 of0 = *(const float4*)(scoff + 128 + kc);
        float4 of1 = *(const float4*)(scoff + 128 + kc + 4);
        float e[8];
        e[0] = fmaf(sc0.x, h01.x, of0.x); e[1] = fmaf(sc0.y, h01.y, of0.y);
        e[2] = fmaf(sc0.z, h23.x, of0.z); e[3] = fmaf(sc0.w, h23.y, of0.w);
        e[4] = fmaf(sc1.x, h45.x, of1.x); e[5] = fmaf(sc1.y, h45.y, of1.y);
        e[6] = fmaf(sc1.z, h67.x, of1.z); e[7] = fmaf(sc1.w, h67.y, of1.w);
        bf16x8 af;
#pragma unroll
        for (int j = 0; j < 8; j++) {
            float v = e[j];
            v = (v > 0.f) ? v : (__expf(v) - 1.f);
            af[j] = (short)f2b(v);
        }
#pragma unroll
        for (int ct = 0; ct < 8; ct++) {
            bf16x8 b = *(const bf16x8*)(ST + (size_t)(ct * 16 + l16) * 128 + quad * 8 + k0);
            acc[ct] = __builtin_amdgcn_mfma_f32_16x16x32_bf16(af, b, acc[ct], 0, 0, 0);
        }
    }
}

// ---------------- fused skip + next-layer dual GEMM ----------------
__global__ void __launch_bounds__(256) k_skip_dual(
    const unsigned short* __restrict__ hbufb, const float* __restrict__ scoff,
    const unsigned short* __restrict__ ST, const float* __restrict__ skip_b,
    unsigned short* __restrict__ Xb16,
    const unsigned short* __restrict__ WTnext, unsigned short* __restrict__ xlr) {
    __shared__ unsigned short tileX[64][136];      // block-wide new X (bf16)
    __shared__ unsigned short tileC[4][16][264];   // per-wave xlr staging
    int t = threadIdx.x;
    int w = t >> 6, lane = t & 63;
    int quad = lane >> 4, l16 = lane & 15;
    int r0b = blockIdx.x * 64;
    int r0 = r0b + w * 16;
    int lrow = r0 + l16; if (lrow >= NN) lrow = NN - 1;
#pragma unroll
    for (int it = 0; it < 4; it++) {
        int idx = it * 256 + t;
        int row = idx >> 4;
        int c8 = (idx & 15) * 8;
        int rr = r0b + row;
        uint4 v = (rr < NN) ? *(const uint4*)&Xb16[(size_t)rr * 128 + c8]
                            : (uint4){0, 0, 0, 0};
        *(uint4*)&tileX[row][c8] = v;
    }
    f32x4 acc[8];
    skip_core(hbufb, scoff, ST, lrow, quad, l16, acc);
    __syncthreads();
#pragma unroll
    for (int ct = 0; ct < 8; ct++) {
        int c = ct * 16 + l16;
        float sb = skip_b[c];
#pragma unroll
        for (int r = 0; r < 4; r++) {
            int wrow = w * 16 + quad * 4 + r;
            float v = b2f(tileX[wrow][c]) + acc[ct][r] + sb;
            tileX[wrow][c] = f2b(v);
        }
    }
    __syncthreads();
#pragma unroll
    for (int it = 0; it < 4; it++) {
        int idx = it * 256 + t;
        int row = idx >> 4;
        int c8 = (idx & 15) * 8;
        int rr = r0b + row;
        if (rr < NN) *(uint4*)&Xb16[(size_t)rr * 128 + c8] = *(const uint4*)&tileX[row][c8];
    }
    int wrowA = w * 16 + l16;
    bf16x8 a[4];
#pragma unroll
    for (int ks = 0; ks < 4; ks++)
        a[ks] = *(const bf16x8*)&tileX[wrowA][quad * 8 + ks * 32];
    f32x4 dacc[16];
#pragma unroll
    for (int ct = 0; ct < 16; ct++) dacc[ct] = (f32x4){0, 0, 0, 0};
#pragma unroll
    for (int ct = 0; ct < 16; ct++) {
        const unsigned short* bbase = WTnext + (size_t)(ct * 16 + l16) * 128 + quad * 8;
#pragma unroll
        for (int ks = 0; ks < 4; ks++) {
            bf16x8 b = *(const bf16x8*)(bbase + ks * 32);
            dacc[ct] = __builtin_amdgcn_mfma_f32_16x16x32_bf16(a[ks], b, dacc[ct], 0, 0, 0);
        }
    }
#pragma unroll
    for (int ct = 0; ct < 16; ct++) {
#pragma unroll
        for (int r = 0; r < 4; r++)
            tileC[w][quad * 4 + r][ct * 16 + l16] = f2b(dacc[ct][r]);
    }
    __syncthreads();
#pragma unroll
    for (int it = 0; it < 8; it++) {
        int idx = it * 64 + lane;
        int row = idx >> 5;
        int c8 = (idx & 31) * 8;
        int rr = r0 + row;
        if (rr < NN) *(uint4*)&xlr[(size_t)rr * 256 + c8] = *(const uint4*)&tileC[w][row][c8];
    }
}

// ---------------- fused skip + final fc (last layer) ----------------
__global__ void __launch_bounds__(256) k_skip_fc(
    const unsigned short* __restrict__ hbufb, const float* __restrict__ scoff,
    const unsigned short* __restrict__ ST, const float* __restrict__ skip_b,
    const unsigned short* __restrict__ Xb16,
    const float* __restrict__ fc_W, const float* __restrict__ fc_b,
    float* __restrict__ out) {
    __shared__ unsigned short tileX[64][136];
    int t = threadIdx.x;
    int w = t >> 6, lane = t & 63;
    int quad = lane >> 4, l16 = lane & 15;
    int r0b = blockIdx.x * 64;
    int r0 = r0b + w * 16;
    int lrow = r0 + l16; if (lrow >= NN) lrow = NN - 1;
#pragma unroll
    for (int it = 0; it < 4; it++) {
        int idx = it * 256 + t;
        int row = idx >> 4;
        int c8 = (idx & 15) * 8;
        int rr = r0b + row;
        uint4 v = (rr < NN) ? *(const uint4*)&Xb16[(size_t)rr * 128 + c8]
                            : (uint4){0, 0, 0, 0};
        *(uint4*)&tileX[row][c8] = v;
    }
    f32x4 acc[8];
    skip_core(hbufb, scoff, ST, lrow, quad, l16, acc);
    __syncthreads();
    float p[4] = {0.f, 0.f, 0.f, 0.f};
#pragma unroll
    for (int ct = 0; ct < 8; ct++) {
        int c = ct * 16 + l16;
        float sb = skip_b[c];
        float fw = fc_W[c];
#pragma unroll
        for (int r = 0; r < 4; r++) {
            int wrow = w * 16 + quad * 4 + r;
            float v = b2f(tileX[wrow][c]) + acc[ct][r] + sb;
            p[r] = fmaf(v, fw, p[r]);
        }
    }
#pragma unroll
    for (int r = 0; r < 4; r++) {
        p[r] += __shfl_xor(p[r], 1);
        p[r] += __shfl_xor(p[r], 2);
        p[r] += __shfl_xor(p[r], 4);
        p[r] += __shfl_xor(p[r], 8);
    }
    if (l16 == 0) {
        float fb = fc_b[0];
#pragma unroll
        for (int r = 0; r < 4; r++) {
            int rr = r0 + quad * 4 + r;
            if (rr < NN) out[rr] = p[r] + fb;
        }
    }
}

// ---------------- fused GATv2 (R15 structure, exp2f): 8 slots stride one node ----------------
__global__ void __launch_bounds__(128) k_gat_node(
    const unsigned short* __restrict__ xlr,
    const float* __restrict__ att, const float* __restrict__ conv_b,
    const int* __restrict__ row_ptr, const int* __restrict__ csr_off,
    unsigned short* __restrict__ houtb, float* __restrict__ stats) {
    int t = threadIdx.x;
    int g = t >> 4;          // slot 0..7
    int l = t & 15;          // lane in slot: owns channels 8l..8l+7
    const char* xbytes = (const char*)xlr;
    int lofs = 16 * l;
    float2 at2[4];
    {
        float4 a0 = *(const float4*)&att[8 * l];
        float4 a1 = *(const float4*)&att[8 * l + 4];
        at2[0] = make_float2(a0.x * LOG2E, a0.y * LOG2E);
        at2[1] = make_float2(a0.z * LOG2E, a0.w * LOG2E);
        at2[2] = make_float2(a1.x * LOG2E, a1.y * LOG2E);
        at2[3] = make_float2(a1.z * LOG2E, a1.w * LOG2E);
    }
    float cb = conv_b[t];
    int i0 = blockIdx.x * NPB;
    int rp[NPB + 1];
#pragma unroll
    for (int k = 0; k <= NPB; k++) rp[k] = row_ptr[i0 + k];   // wave-uniform -> scalar
    __shared__ float s_acc[2][8][16][12];
    __shared__ float s_den[2][8][16];
    float ssum = 0.f, ssum2 = 0.f;
    uint4 xr_next = *(const uint4*)(xbytes + (size_t)i0 * 512 + 256 + lofs);
    for (int nn = 0; nn < NPB; nn++) {
        int i = i0 + nn;
        uint4 xr_raw = xr_next;
        if (nn + 1 < NPB)
            xr_next = *(const uint4*)(xbytes + (size_t)(i + 1) * 512 + 256 + lofs);
        float2 xr2[4];
        xr2[0] = up2(xr_raw.x); xr2[1] = up2(xr_raw.y);
        xr2[2] = up2(xr_raw.z); xr2[3] = up2(xr_raw.w);
        int start = rp[nn], end = rp[nn + 1];
        float den = 0.f;
        float2 acc[4];
#pragma unroll
        for (int k = 0; k < 4; k++) acc[k] = make_float2(0.f, 0.f);
        int j = start + g;
        bool v0 = j < end;
        int o0 = v0 ? csr_off[j] : 0;
        bool v1 = (j + 8) < end;
        int o1 = v1 ? csr_off[j + 8] : 0;
        uint4 xw0 = {0,0,0,0}, xw1 = {0,0,0,0};
        if (v0) xw0 = *(const uint4*)(xbytes + (size_t)(unsigned)o0 + lofs);
        if (v1) xw1 = *(const uint4*)(xbytes + (size_t)(unsigned)o1 + lofs);
        while (v0) {
            bool v2 = (j + 16) < end;
            int o2 = v2 ? csr_off[j + 16] : 0;
            uint4 xw2 = {0,0,0,0};
            if (v2) xw2 = *(const uint4*)(xbytes + (size_t)(unsigned)o2 + lofs);
            float2 f0 = up2(xw0.x), f1 = up2(xw0.y), f2v = up2(xw0.z), f3 = up2(xw0.w);
            float2 ps = make_float2(0.f, 0.f);
            ps = pk_fma(at2[0], pk_leaky(pk_add(f0, xr2[0])), ps);
            ps = pk_fma(at2[1], pk_leaky(pk_add(f1, xr2[1])), ps);
            ps = pk_fma(at2[2], pk_leaky(pk_add(f2v, xr2[2])), ps);
            ps = pk_fma(at2[3], pk_leaky(pk_add(f3, xr2[3])), ps);
            float p = ps.x + ps.y;
            p += __shfl_xor(p, 1);   // 4-lane head group
            p += __shfl_xor(p, 2);
            float w = exp2f(p);
            den += w;
            float2 w2 = make_float2(w, w);
            acc[0] = pk_fma(w2, f0, acc[0]);
            acc[1] = pk_fma(w2, f1, acc[1]);
            acc[2] = pk_fma(w2, f2v, acc[2]);
            acc[3] = pk_fma(w2, f3, acc[3]);
            j += 8;
            v0 = v1; v1 = v2;
            xw0 = xw1; xw1 = xw2;
        }
        int par = nn & 1;
        *(float4*)&s_acc[par][g][l][0] = make_float4(acc[0].x, acc[0].y, acc[1].x, acc[1].y);
        *(float4*)&s_acc[par][g][l][4] = make_float4(acc[2].x, acc[2].y, acc[3].x, acc[3].y);
        s_den[par][g][l] = den;
        __syncthreads();
        int cl = t >> 3, cj = t & 7;
        float a = 0.f, d = 0.f;
#pragma unroll
        for (int gg = 0; gg < 8; gg++) {
            a += s_acc[par][gg][cl][cj];
            d += s_den[par][gg][cl];
        }
        float hv = a / d + cb;
        houtb[(size_t)i * HID + t] = f2b(hv);
        ssum += hv;
        ssum2 += hv * hv;
    }
    float* srep = stats + (size_t)(blockIdx.x & (REP - 1)) * 256;
    atomicAdd(&srep[t], ssum);
    atomicAdd(&srep[128 + t], ssum2);
}

extern "C" void kernel_launch(void* const* d_in, const int* in_sizes, int n_in,
                              void* d_out, int out_size, void* d_ws, size_t ws_size,
                              hipStream_t stream) {
    const float* x_in   = (const float*)d_in[0];
    const int*   ei     = (const int*)d_in[1];
    const float* Wl     = (const float*)d_in[2];
    const float* Wr     = (const float*)d_in[3];
    const float* att    = (const float*)d_in[4];
    const float* conv_b = (const float*)d_in[5];
    const float* gn_w   = (const float*)d_in[6];
    const float* gn_b   = (const float*)d_in[7];
    const float* gn_ms  = (const float*)d_in[8];
    const float* skip_W = (const float*)d_in[9];
    const float* skip_b = (const float*)d_in[10];
    const float* fc_W   = (const float*)d_in[11];
    const float* fc_b   = (const float*)d_in[12];
    float* out = (float*)d_out;

    // workspace carve
    float* ws = (float*)d_ws;
    float* stats = ws;                              // REP * 256
    float* scoff = stats + REP * 256;               // 256
    unsigned short* xlr   = (unsigned short*)(scoff + 256);  // N*256 bf16
    unsigned short* b16X  = xlr + (size_t)NN * 256; // N*HID bf16 (residual stream)
    unsigned short* hbufb = b16X + NN * HID;        // N*HID bf16
    unsigned short* wt    = hbufb + NN * HID;       // 4*256*128
    unsigned short* st    = wt + 4 * 256 * 128;     // 128*128
    int* row_ptr = (int*)(st + 128 * 128);          // N+1
    int* bcnt    = row_ptr + NN + 1;                // NB
    int* csr_off = bcnt + NB;                       // NE (byte offsets)
    unsigned* bbuf = (unsigned*)(csr_off + NE);     // NB*BCAP

    k_prep<<<(NN * HID / 4 + 255) / 256, 256, 0, stream>>>(
        x_in, Wl, Wr, skip_W, b16X, wt, st, bcnt, stats);

    // CSR build via bucket sort
    k_bin<<<(NE + TB - 1) / TB, 256, 0, stream>>>(ei, bcnt, bbuf);
    k_bucket_csr<<<NB, 256, 0, stream>>>(bbuf, bcnt, row_ptr, csr_off);

    const int rtiles = (NN + 63) / 64;              // 782
    const int gat_blocks = (NN + NPB - 1) / NPB;    // 6250
    k_gemm_dual_mfma<<<rtiles, 256, 0, stream>>>(b16X, wt, xlr);
    for (int l = 0; l < 4; l++) {
        k_gat_node<<<gat_blocks, 128, 0, stream>>>(
            xlr, att + l * HID, conv_b + l * HID, row_ptr, csr_off,
            hbufb, stats);
        k_finalize<<<1, 1024, 0, stream>>>(stats, gn_w + l * HID,
                                           gn_b + l * HID, gn_ms + l * HID, scoff);
        if (l < 3) {
            k_skip_dual<<<rtiles, 256, 0, stream>>>(
                hbufb, scoff, st, skip_b, b16X,
                wt + (size_t)(l + 1) * 256 * 128, xlr);
        } else {
            k_skip_fc<<<rtiles, 256, 0, stream>>>(
                hbufb, scoff, st, skip_b, b16X, fc_W, fc_b, out);
        }
    }
}